// Round 7
// baseline (93.532 us; speedup 1.0000x reference)
//
#include <hip/hip_runtime.h>

// SparseConv1D on MI355X, round 6.
// out[b,o,l] = sum_{t,i} W[o,i,t] * x[b,i,l+tap_t] = 32 shifted GEMMs (MFMA 16x16x32 bf16).
// R6 vs R5 (R3/R4/R5 all bounced off ~93us -> sconv pinned by per-tap PHASE LOCK:
// [read burst][MFMA burst] serialized by the barrier):
//  - IN-WAVE FRAG PREFETCH: at iter t, ds_read tap t+1's frags into the other register
//    buffer (independent of tap t's MFMAs) -> LDS port and MFMA pipe overlap inside one
//    wave. Needs staging lookahead depth 2 (stage(t+2) issued at iter t).
//  - 1024-row ring (128KB) + W dbuf 16KB = 144KB LDS; 512-thread block, tile 64o x 256l,
//    grid 256 = 1 block/CU, 8 waves/CU (k-split: lh 0..3, ch 0..1; wave = 64o x 64l x 32i).
//  - Delta staging: ~1280 rows/block total vs 8192 full-restage; W 8KB/tap/block.

#define B_    16
#define CIN   64
#define COUT  64
#define LEN   4096
#define PAD_LO 512
#define PAD_HI 256
#define LPAD  (LEN + PAD_LO + PAD_HI)   // 4864
#define NTAP  32
#define WOFF  131072                     // ring = 1024 rows x 128B; W dbuf above it

typedef float f32x4 __attribute__((ext_vector_type(4)));
typedef short bf16x8_s __attribute__((ext_vector_type(8)));
typedef __bf16 bf16x8_b __attribute__((ext_vector_type(8)));
typedef unsigned short u16x8 __attribute__((ext_vector_type(8)));

template <typename V>
static __device__ inline auto mfma_16x16x32_bf16(V a, V b, f32x4 c, int)
    -> decltype(__builtin_amdgcn_mfma_f32_16x16x32_bf16(a, b, c, 0, 0, 0)) {
  return __builtin_amdgcn_mfma_f32_16x16x32_bf16(a, b, c, 0, 0, 0);
}
template <typename V>
static __device__ inline f32x4 mfma_16x16x32_bf16(V a, V b, f32x4 c, long) {
  return __builtin_amdgcn_mfma_f32_16x16x32_bf16(
      __builtin_bit_cast(bf16x8_b, a), __builtin_bit_cast(bf16x8_b, b), c, 0, 0, 0);
}

static __device__ inline unsigned short f32_to_bf16_rne(float f) {
  unsigned int u = __builtin_bit_cast(unsigned int, f);
  u += 0x7fffu + ((u >> 16) & 1u);
  return (unsigned short)(u >> 16);
}

// async 16B/lane global->LDS; lds dest is the wave-uniform base (HW adds lane*16)
static __device__ inline void async_copy16(const void* g, void* l) {
  __builtin_amdgcn_global_load_lds((const __attribute__((address_space(1))) unsigned int*)g,
                                   (__attribute__((address_space(3))) unsigned int*)l, 16, 0, 0);
}

// ---------------- prep: x[b][i][l] fp32 -> Xp[b][lp][i] bf16 (padded) -------------
__global__ __launch_bounds__(256) void prep_x(const float* __restrict__ x,
                                              unsigned short* __restrict__ xp) {
  __shared__ float tile[64][65];
  const int b = blockIdx.y;
  const int lp0 = blockIdx.x * 64;
  const int tid = threadIdx.x;
  const bool data = (lp0 >= PAD_LO) && (lp0 < PAD_LO + LEN);
  if (data) {
    const int l0 = lp0 - PAD_LO;
#pragma unroll
    for (int it = 0; it < 4; ++it) {
      const int pidx = it * 256 + tid;
      const int il = pidx >> 4;          // channel
      const int lq = (pidx & 15) * 4;    // 4 consecutive l
      const float4 v = *(const float4*)&x[(size_t)(b * CIN + il) * LEN + l0 + lq];
      tile[lq + 0][il] = v.x;
      tile[lq + 1][il] = v.y;
      tile[lq + 2][il] = v.z;
      tile[lq + 3][il] = v.w;
    }
  }
  __syncthreads();
#pragma unroll
  for (int it = 0; it < 2; ++it) {
    const int pidx = it * 256 + tid;
    const int ll = pidx >> 3;
    const int i8 = (pidx & 7) * 8;
    u16x8 v = {0, 0, 0, 0, 0, 0, 0, 0};
    if (data) {
#pragma unroll
      for (int j = 0; j < 8; ++j) v[j] = f32_to_bf16_rne(tile[ll][i8 + j]);
    }
    *(u16x8*)&xp[(size_t)(b * LPAD + lp0 + ll) * CIN + i8] = v;
  }
}

// ------ prep: w[o][i][t] fp32 -> Wf[t][c][m][lane][8] bf16 (frag-major, 8KB/tap) ---
// A-frag content: W[o = 16m + (lane&15)][i = c*32 + (lane>>4)*8 + j][t]
__global__ __launch_bounds__(256) void prep_w(const float* __restrict__ w,
                                              unsigned short* __restrict__ wf) {
  const int e = blockIdx.x * 256 + threadIdx.x;  // < 32*2*4*64*8 = 131072
  const int j = e & 7;
  const int lane = (e >> 3) & 63;
  const int m = (e >> 9) & 3;
  const int c = (e >> 11) & 1;
  const int t = e >> 12;
  const int q = lane >> 4, r = lane & 15;
  const int o = m * 16 + r;
  const int i = c * 32 + q * 8 + j;
  wf[e] = f32_to_bf16_rne(w[(size_t)(o * CIN + i) * NTAP + t]);
}

// ------- main: in-wave frag prefetch + depth-2 delta staging, 1 block/CU ---------
__global__ __launch_bounds__(512, 2) void sconv_main(const unsigned short* __restrict__ xp,
                                                     const unsigned short* __restrict__ wf,
                                                     float* __restrict__ out) {
  constexpr int TAP[NTAP] = {-512, -256, -128, -96, -64, -48, -32, -24, -16, -12, -8,
                             -6,   -4,   -3,   -2,  -1,  0,   1,   2,   3,   4,  6,
                             8,    12,   16,   24,  32,  48,  64,  96,  128, 256};
  __shared__ alignas(16) char smem[WOFF + 16384];  // ring 1024x128B + W dbuf 2x8KB

  const int id = blockIdx.x;
  const int b = (id & 7) * 2 + (id >> 7);   // XCD k <- batches {2k,2k+1}
  const int l0 = ((id >> 3) & 15) * 256;    // 16 l-tiles of 256
  const int lb = l0 + PAD_LO;               // absolute padded base row (mult of 256)
  const int tid = threadIdx.x;
  const int wv = tid >> 6, lane = tid & 63;
  const int q = lane >> 4, r = lane & 15;
  const int lh = wv >> 1, ch = wv & 1;      // wave: l-quarter lh (64 l), i-half ch

  const char* xbase = (const char*)xp + ((size_t)b * LPAD + lb) * (CIN * 2);
  const char* wbase = (const char*)wf;

  auto stageW = [&](int t) {
    async_copy16(wbase + t * 8192 + (wv * 64 + lane) * 16,
                 smem + WOFF + (t & 1) * 8192 + wv * 1024);
  };
  // stage relative rows [a0, a0+8*ng) into ring; a0 8-aligned.
  // LDS[slot][c'] = G[row][c' ^ (row&7)]
  auto stageB = [&](int a0, int ng) {
    for (int g = wv; g < ng; g += 8) {
      const int ra = a0 + g * 8 + (lane >> 3);
      const int cs = (lane & 7) ^ (ra & 7);
      const int sb = (lb + a0 + g * 8) & 1023;     // 8-aligned group, never wraps
      async_copy16(xbase + (ptrdiff_t)ra * 128 + cs * 16, smem + sb * 128);
    }
  };

  f32x4 acc[4][4] = {};
  bf16x8_s Ab[2][4], Bb[2][4];

  // frag read for tap tt into buffer p
  auto readFrags = [&](int tt, int p) {
    const char* Wb = smem + WOFF + (tt & 1) * 8192 + ch * 4096;
#pragma unroll
    for (int m = 0; m < 4; ++m)
      Ab[p][m] = *(const bf16x8_s*)(Wb + m * 1024 + lane * 16);
    const int e = (TAP[tt] + r) & 7;         // == row&7 for this lane's B rows
#pragma unroll
    for (int n = 0; n < 4; ++n) {
      const int slot = (lb + TAP[tt] + lh * 64 + 16 * n + r) & 1023;
      Bb[p][n] = *(const bf16x8_s*)(smem + slot * 128 + (((ch * 4 + q) ^ e) << 4));
    }
  };

  // prologue: W(0),W(1); ring rows [-512,0) = window(0) + delta(1)
  stageW(0);
  stageW(1);
  stageB(-512, 64);
  __syncthreads();
  readFrags(0, 0);

#pragma unroll
  for (int t = 0; t < NTAP; ++t) {
    __syncthreads();                       // stage(t+1) (issued at t-1) is now resident
    if (t + 2 < NTAP) {
      stageW(t + 2);
      const int dstart = TAP[t + 1] + 256; // delta rows for window t+2
      const int dend = TAP[t + 2] + 256;
      const int a0 = dstart & ~7;          // <=7 identical-rewrite rows: benign
      stageB(a0, (dend - a0 + 7) >> 3);
    }
    __builtin_amdgcn_sched_barrier(0);
    if (t + 1 < NTAP) readFrags(t + 1, (t + 1) & 1);   // overlaps tap t's MFMAs
    __builtin_amdgcn_sched_barrier(0);
    const int p = t & 1;
#pragma unroll
    for (int m = 0; m < 4; ++m)
#pragma unroll
      for (int n = 0; n < 4; ++n)
        acc[m][n] = mfma_16x16x32_bf16(Ab[p][m], Bb[p][n], acc[m][n], 0);
  }

  // ---- reduce the two i-halves through LDS (ring area is dead now) ----
  __syncthreads();
  if (ch == 1) {
#pragma unroll
    for (int m = 0; m < 4; ++m)
#pragma unroll
      for (int n = 0; n < 4; ++n)
        *(f32x4*)(smem + lh * 16384 + ((m * 4 + n) * 64 + lane) * 16) = acc[m][n];
  }
  __syncthreads();
  if (ch == 0) {
#pragma unroll
    for (int m = 0; m < 4; ++m)
#pragma unroll
      for (int n = 0; n < 4; ++n) {
        const f32x4 other = *(const f32x4*)(smem + lh * 16384 + ((m * 4 + n) * 64 + lane) * 16);
        const f32x4 v = acc[m][n] + other;
        // C/D layout (verified): col(l) = lane&15, row(o) = (lane>>4)*4 + reg
#pragma unroll
        for (int d = 0; d < 4; ++d) {
          const int o = 16 * m + 4 * q + d;
          const int l = l0 + lh * 64 + 16 * n + r;
          out[((size_t)b * COUT + o) * LEN + l] = v[d];
        }
      }
  }
}

extern "C" void kernel_launch(void* const* d_in, const int* in_sizes, int n_in,
                              void* d_out, int out_size, void* d_ws, size_t ws_size,
                              hipStream_t stream) {
  const float* x = (const float*)d_in[0];        // [16][64][4096]
  const float* w = (const float*)d_in[1];        // [64][64][32]
  float* out = (float*)d_out;                    // [16][64][4096]

  unsigned short* xp = (unsigned short*)d_ws;                    // 16*4864*64 bf16 = 9.96 MB
  unsigned short* wfp = xp + (size_t)B_ * LPAD * CIN;            // 256 KB

  prep_x<<<dim3(LPAD / 64, B_), 256, 0, stream>>>(x, xp);
  prep_w<<<dim3((NTAP * 2 * 4 * 64 * 8) / 256), 256, 0, stream>>>(w, wfp);
  sconv_main<<<dim3(256), 512, 0, stream>>>(xp, wfp, out);
}

// Round 8
// 89.879 us; speedup vs baseline: 1.0406x; 1.0406x over previous
//
#include <hip/hip_runtime.h>

// SparseConv1D on MI355X, round 7.
// out[b,o,l] = sum_{t,i} W[o,i,t] * x[b,i,l+tap_t] = 32 shifted GEMMs (MFMA 16x16x32 bf16).
// R7 vs R6 (five sconv-loop restructures all flat at ~93us; LDS-read floor 10.2us was
// the binding resource, barrier x32 the tax):
//  - W NEVER TOUCHES LDS: A-frags loaded global->register (frag-major, coalesced,
//    L1-broadcast across lh-waves), 2-deep dbuf prefetched 1 tap ahead. LDS reads halve
//    (only B): floor 5.1us -> MFMA (8.3us) becomes the binding pipe.
//  - Taps chunked x4: ONE __syncthreads per chunk (9 barriers vs 34). Delta staging for
//    chunk g+1 issued at chunk g start (~2500cyc slack). Ring 1024 rows: max span
//    TAP[t+7]-TAP[t]+255 = 743 < 1024, WAR-safe.
//  - B-frags reg-dbuffed too (read t+1 during t's MFMAs, within-chunk).
//  - prep_w fused into prep_x pad-blocks (one launch fewer).

#define B_    16
#define CIN   64
#define COUT  64
#define LEN   4096
#define PAD_LO 512
#define PAD_HI 256
#define LPAD  (LEN + PAD_LO + PAD_HI)   // 4864
#define NTAP  32

typedef float f32x4 __attribute__((ext_vector_type(4)));
typedef short bf16x8_s __attribute__((ext_vector_type(8)));
typedef __bf16 bf16x8_b __attribute__((ext_vector_type(8)));
typedef unsigned short u16x8 __attribute__((ext_vector_type(8)));

template <typename V>
static __device__ inline auto mfma_16x16x32_bf16(V a, V b, f32x4 c, int)
    -> decltype(__builtin_amdgcn_mfma_f32_16x16x32_bf16(a, b, c, 0, 0, 0)) {
  return __builtin_amdgcn_mfma_f32_16x16x32_bf16(a, b, c, 0, 0, 0);
}
template <typename V>
static __device__ inline f32x4 mfma_16x16x32_bf16(V a, V b, f32x4 c, long) {
  return __builtin_amdgcn_mfma_f32_16x16x32_bf16(
      __builtin_bit_cast(bf16x8_b, a), __builtin_bit_cast(bf16x8_b, b), c, 0, 0, 0);
}

static __device__ inline unsigned short f32_to_bf16_rne(float f) {
  unsigned int u = __builtin_bit_cast(unsigned int, f);
  u += 0x7fffu + ((u >> 16) & 1u);
  return (unsigned short)(u >> 16);
}

// async 16B/lane global->LDS; lds dest is the wave-uniform base (HW adds lane*16)
static __device__ inline void async_copy16(const void* g, void* l) {
  __builtin_amdgcn_global_load_lds((const __attribute__((address_space(1))) unsigned int*)g,
                                   (__attribute__((address_space(3))) unsigned int*)l, 16, 0, 0);
}

// ---- fused prep: x[b][i][l] f32 -> Xp[b][lp][i] bf16 (padded); pad-blocks also do
// ---- w[o][i][t] f32 -> Wf[t][c][m][lane][8] bf16 (frag-major, 8KB/tap)
__global__ __launch_bounds__(256) void prep_xw(const float* __restrict__ x,
                                               const float* __restrict__ w,
                                               unsigned short* __restrict__ xp,
                                               unsigned short* __restrict__ wf) {
  __shared__ float tile[64][65];
  const int b = blockIdx.y;
  const int lp0 = blockIdx.x * 64;
  const int tid = threadIdx.x;
  const bool data = (lp0 >= PAD_LO) && (lp0 < PAD_LO + LEN);
  if (data) {
    const int l0 = lp0 - PAD_LO;
#pragma unroll
    for (int it = 0; it < 4; ++it) {
      const int pidx = it * 256 + tid;
      const int il = pidx >> 4;
      const int lq = (pidx & 15) * 4;
      const float4 v = *(const float4*)&x[(size_t)(b * CIN + il) * LEN + l0 + lq];
      tile[lq + 0][il] = v.x;
      tile[lq + 1][il] = v.y;
      tile[lq + 2][il] = v.z;
      tile[lq + 3][il] = v.w;
    }
  } else if (lp0 < PAD_LO) {
    // pad block: also transpose a 1/128 slice of W (16 b * 8 x-blocks = 128 slices)
    const int base = (b * 8 + blockIdx.x) * 1024;
#pragma unroll
    for (int it = 0; it < 4; ++it) {
      const int e = base + it * 256 + tid;   // < 131072
      const int j = e & 7;
      const int lane = (e >> 3) & 63;
      const int m = (e >> 9) & 3;
      const int c = (e >> 11) & 1;
      const int t = e >> 12;
      const int o = m * 16 + (lane & 15);
      const int i = c * 32 + (lane >> 4) * 8 + j;
      wf[e] = f32_to_bf16_rne(w[(size_t)(o * CIN + i) * NTAP + t]);
    }
  }
  __syncthreads();
#pragma unroll
  for (int it = 0; it < 2; ++it) {
    const int pidx = it * 256 + tid;
    const int ll = pidx >> 3;
    const int i8 = (pidx & 7) * 8;
    u16x8 v = {0, 0, 0, 0, 0, 0, 0, 0};
    if (data) {
#pragma unroll
      for (int j = 0; j < 8; ++j) v[j] = f32_to_bf16_rne(tile[ll][i8 + j]);
    }
    *(u16x8*)&xp[(size_t)(b * LPAD + lp0 + ll) * CIN + i8] = v;
  }
}

// ------- main: W global->reg dbuf, B LDS-ring->reg dbuf, 4-tap chunks -------------
__global__ __launch_bounds__(512, 2) void sconv_main(const unsigned short* __restrict__ xp,
                                                     const unsigned short* __restrict__ wf,
                                                     float* __restrict__ out) {
  constexpr int TAP[NTAP] = {-512, -256, -128, -96, -64, -48, -32, -24, -16, -12, -8,
                             -6,   -4,   -3,   -2,  -1,  0,   1,   2,   3,   4,  6,
                             8,    12,   16,   24,  32,  48,  64,  96,  128, 256};
  __shared__ alignas(16) char smem[131072];   // ring: 1024 rows x 128B

  const int id = blockIdx.x;
  const int b = (id & 7) * 2 + (id >> 7);     // XCD k <- batches {2k,2k+1}
  const int l0 = ((id >> 3) & 15) * 256;      // 16 l-tiles of 256
  const int lb = l0 + PAD_LO;                 // absolute padded base row (mult of 256)
  const int tid = threadIdx.x;
  const int wv = tid >> 6, lane = tid & 63;
  const int q = lane >> 4, r = lane & 15;
  const int lh = wv >> 1, ch = wv & 1;        // wave: l-quarter (64 l), i-half (32 i)

  const char* xbase = (const char*)xp + ((size_t)b * LPAD + lb) * (CIN * 2);
  const char* wbase = (const char*)wf;

  // stage relative rows [a0, a0+8*ng) into ring; a0 8-aligned.
  // LDS[slot][c'] = G[row][c' ^ (row&7)]
  auto stageB = [&](int a0, int ng) {
    for (int g = wv; g < ng; g += 8) {
      const int ra = a0 + g * 8 + (lane >> 3);
      const int cs = (lane & 7) ^ (ra & 7);
      const int sb = (lb + a0 + g * 8) & 1023;   // 8-aligned group, never wraps
      async_copy16(xbase + (ptrdiff_t)ra * 128 + cs * 16, smem + sb * 128);
    }
  };

  bf16x8_s Wreg[2][4], Breg[2][4];
  f32x4 acc[4][4] = {};

  auto loadW = [&](int tt, int p) {            // global, frag-major, coalesced
    const char* src = wbase + tt * 8192 + ch * 4096 + lane * 16;
#pragma unroll
    for (int m = 0; m < 4; ++m)
      Wreg[p][m] = *(const bf16x8_s*)(src + m * 1024);
  };
  auto readB = [&](int tt, int p) {
    const int e = (TAP[tt] + r) & 7;           // row&7 for this lane's B rows
#pragma unroll
    for (int n = 0; n < 4; ++n) {
      const int slot = (lb + TAP[tt] + lh * 64 + 16 * n + r) & 1023;
      Breg[p][n] = *(const bf16x8_s*)(smem + slot * 128 + (((ch * 4 + q) ^ e) << 4));
    }
  };

  // prologue: W(0) to regs; ring rows [-512,160) = union of windows for taps 0..3
  loadW(0, 0);
  stageB(-512, 84);

#pragma unroll
  for (int g = 0; g < 8; ++g) {
    __syncthreads();                           // chunk g's ring rows are resident
    readB(4 * g, 0);                           // tap 4g (parity 0)
    if (g < 7) {                               // stage delta for chunk g+1
      const int dstart = TAP[4 * g + 3] + 256;
      const int dend = TAP[4 * g + 7] + 256;
      const int a0 = dstart & ~7;              // <=7 identical-rewrite rows: benign
      stageB(a0, (dend - a0 + 7) >> 3);
    }
    __builtin_amdgcn_sched_barrier(0);         // pin staging issue above compute
#pragma unroll
    for (int u = 0; u < 4; ++u) {
      const int t = 4 * g + u, p = t & 1;
      if (t + 1 < NTAP) {
        loadW(t + 1, p ^ 1);                   // global prefetch, no barrier needed
        if ((t + 1) & 3) readB(t + 1, p ^ 1);  // within-chunk B prefetch
      }
      __builtin_amdgcn_sched_barrier(0);       // don't sink prefetch below MFMAs
#pragma unroll
      for (int m = 0; m < 4; ++m)
#pragma unroll
        for (int n = 0; n < 4; ++n)
          acc[m][n] = mfma_16x16x32_bf16(Wreg[p][m], Breg[p][n], acc[m][n], 0);
    }
  }

  // ---- reduce the two i-halves through LDS (ring is dead now) ----
  __syncthreads();
  if (ch == 1) {
#pragma unroll
    for (int m = 0; m < 4; ++m)
#pragma unroll
      for (int n = 0; n < 4; ++n)
        *(f32x4*)(smem + lh * 16384 + ((m * 4 + n) * 64 + lane) * 16) = acc[m][n];
  }
  __syncthreads();
  if (ch == 0) {
#pragma unroll
    for (int m = 0; m < 4; ++m)
#pragma unroll
      for (int n = 0; n < 4; ++n) {
        const f32x4 other = *(const f32x4*)(smem + lh * 16384 + ((m * 4 + n) * 64 + lane) * 16);
        const f32x4 v = acc[m][n] + other;
        // C/D layout (verified): col(l) = lane&15, row(o) = (lane>>4)*4 + reg
#pragma unroll
        for (int d = 0; d < 4; ++d) {
          const int o = 16 * m + 4 * q + d;
          const int l = l0 + lh * 64 + 16 * n + r;
          out[((size_t)b * COUT + o) * LEN + l] = v[d];
        }
      }
  }
}

extern "C" void kernel_launch(void* const* d_in, const int* in_sizes, int n_in,
                              void* d_out, int out_size, void* d_ws, size_t ws_size,
                              hipStream_t stream) {
  const float* x = (const float*)d_in[0];        // [16][64][4096]
  const float* w = (const float*)d_in[1];        // [64][64][32]
  float* out = (float*)d_out;                    // [16][64][4096]

  unsigned short* xp = (unsigned short*)d_ws;                    // 16*4864*64 bf16 = 9.96 MB
  unsigned short* wfp = xp + (size_t)B_ * LPAD * CIN;            // 256 KB

  prep_xw<<<dim3(LPAD / 64, B_), 256, 0, stream>>>(x, w, xp, wfp);
  sconv_main<<<dim3(256), 512, 0, stream>>>(xp, wfp, out);
}